// Round 1
// baseline (92.162 us; speedup 1.0000x reference)
//
#include <hip/hip_runtime.h>
#include <cstdint>

#define N_NODES 4096
#define N_EDGES 131072
#define MASK_WORDS (N_NODES * N_NODES / 32)  // 524288 u32 = 2 MB per mask

// ---- zero the two bitmasks (harness poisons d_ws with 0xAA before every call)
__global__ void zero_ws_kernel(uint4* __restrict__ ws) {
    int idx = blockIdx.x * blockDim.x + threadIdx.x;
    ws[idx] = make_uint4(0u, 0u, 0u, 0u);
}

// ---- scatter both edge lists into bitmasks
__global__ void scatter_edges_kernel(const int* __restrict__ et,
                                     const int* __restrict__ es,
                                     uint32_t* __restrict__ mask_t,
                                     uint32_t* __restrict__ mask_s) {
    int e = blockIdx.x * blockDim.x + threadIdx.x;
    if (e >= N_EDGES) return;
    {
        uint32_t i = (uint32_t)et[e];
        uint32_t j = (uint32_t)et[N_EDGES + e];
        uint32_t pos = i * N_NODES + j;
        atomicOr(&mask_t[pos >> 5], 1u << (pos & 31));
    }
    {
        uint32_t i = (uint32_t)es[e];
        uint32_t j = (uint32_t)es[N_EDGES + e];
        uint32_t pos = i * N_NODES + j;
        atomicOr(&mask_s[pos >> 5], 1u << (pos & 31));
    }
}

// ---- one block per row i: out[tri(i,j)] = vals[(s<<1)|t] for j in (i, N)
__global__ void fill_kernel(const float* __restrict__ Qt,
                            const int* __restrict__ t_ptr,
                            const uint32_t* __restrict__ mask_t,
                            const uint32_t* __restrict__ mask_s,
                            float* __restrict__ out) {
    const int t = t_ptr[0];
    // Q_likelihood[1, a_t] = Qt[0][1][a_t] = Qt[2 + a_t]
    const float l0 = Qt[2], l1 = Qt[3];
    // Q_prior[a_s, 1] = Qt[t-1][a_s][1]
    const float p0 = Qt[(t - 1) * 4 + 1], p1 = Qt[(t - 1) * 4 + 3];
    // Q_evidence[a_s, a_t] = Qt[t][a_s][a_t]
    const float e00 = Qt[t * 4 + 0], e01 = Qt[t * 4 + 1];
    const float e10 = Qt[t * 4 + 2], e11 = Qt[t * 4 + 3];
    float vals[4];
    vals[0] = l0 * p0 / e00;  // s=0, t=0
    vals[1] = l1 * p0 / e01;  // s=0, t=1
    vals[2] = l0 * p1 / e10;  // s=1, t=0
    vals[3] = l1 * p1 / e11;  // s=1, t=1

    const int i = blockIdx.x;            // 0 .. N-2
    // row-major triu(k=1) linearization: offset of row i
    const int base = i * (2 * N_NODES - i - 1) / 2;
    const uint32_t rowbits = (uint32_t)i * N_NODES;

    for (int j = i + 1 + threadIdx.x; j < N_NODES; j += blockDim.x) {
        uint32_t pos = rowbits + (uint32_t)j;
        uint32_t bt = (mask_t[pos >> 5] >> (pos & 31)) & 1u;
        uint32_t bs = (mask_s[pos >> 5] >> (pos & 31)) & 1u;
        out[base + (j - i - 1)] = vals[(bs << 1) | bt];
    }
}

extern "C" void kernel_launch(void* const* d_in, const int* in_sizes, int n_in,
                              void* d_out, int out_size, void* d_ws, size_t ws_size,
                              hipStream_t stream) {
    const float* Qt = (const float*)d_in[0];
    const int* et = (const int*)d_in[1];
    const int* es = (const int*)d_in[2];
    const int* t_ptr = (const int*)d_in[3];
    float* out = (float*)d_out;

    uint32_t* mask_t = (uint32_t*)d_ws;
    uint32_t* mask_s = mask_t + MASK_WORDS;

    // 2 masks * 2 MB = 4 MB = 262144 uint4
    zero_ws_kernel<<<(2 * MASK_WORDS / 4) / 256, 256, 0, stream>>>((uint4*)d_ws);
    scatter_edges_kernel<<<N_EDGES / 256, 256, 0, stream>>>(et, es, mask_t, mask_s);
    fill_kernel<<<N_NODES - 1, 256, 0, stream>>>(Qt, t_ptr, mask_t, mask_s, out);
}

// Round 2
// 81.622 us; speedup vs baseline: 1.1291x; 1.1291x over previous
//
#include <hip/hip_runtime.h>
#include <cstdint>

#define N_NODES 4096
#define N_EDGES 131072
// out_size = N*(N-1)/2 = 8386560 floats; divisible by 4 -> 2096640 uint4
#define OUT_QUADS (N_NODES * (N_NODES - 1) / 2 / 4)

// Compute the 4 candidate values exactly like the reference (l * p / e),
// then force LSB tags: index 0 -> LSB 0, 1 -> LSB 1, 2 -> LSB 0, 3 -> LSB 1.
__device__ __forceinline__ void compute_vals(const float* __restrict__ Qt,
                                             const int* __restrict__ t_ptr,
                                             float* vals) {
    const int t = t_ptr[0];
    const float l0 = Qt[2], l1 = Qt[3];                       // Qt[0][1][bt]
    const float p0 = Qt[(t - 1) * 4 + 1], p1 = Qt[(t - 1) * 4 + 3];  // Qt[t-1][bs][1]
    const float e00 = Qt[t * 4 + 0], e01 = Qt[t * 4 + 1];
    const float e10 = Qt[t * 4 + 2], e11 = Qt[t * 4 + 3];
    float v0 = l0 * p0 / e00;  // bs=0, bt=0
    float v1 = l1 * p0 / e01;  // bs=0, bt=1
    float v2 = l0 * p1 / e10;  // bs=1, bt=0
    float v3 = l1 * p1 / e11;  // bs=1, bt=1
    uint32_t u0 = __float_as_uint(v0) & ~1u;
    uint32_t u1 = __float_as_uint(v1) |  1u;
    uint32_t u2 = __float_as_uint(v2) & ~1u;
    uint32_t u3 = __float_as_uint(v3) |  1u;
    vals[0] = __uint_as_float(u0);
    vals[1] = __uint_as_float(u1);
    vals[2] = __uint_as_float(u2);
    vals[3] = __uint_as_float(u3);
}

// triangle-linear index for i<j
__device__ __forceinline__ int tri_idx(int i, int j) {
    return i * (2 * N_NODES - i - 1) / 2 + (j - i - 1);
}

// Pass 1: fill entire output with vals[0] (LSB=0). Fully coalesced uint4.
__global__ void gt_fill_default(const float* __restrict__ Qt,
                                const int* __restrict__ t_ptr,
                                float4* __restrict__ out) {
    float vals[4];
    compute_vals(Qt, t_ptr, vals);
    const float4 v = make_float4(vals[0], vals[0], vals[0], vals[0]);
    int idx = blockIdx.x * blockDim.x + threadIdx.x;  // exactly OUT_QUADS threads
    out[idx] = v;
}

// Pass 2: mark x_t edges (i<j) with vals[1] (LSB=1 tag). Plain stores.
__global__ void gt_scatter_t(const float* __restrict__ Qt,
                             const int* __restrict__ t_ptr,
                             const int* __restrict__ et,
                             float* __restrict__ out) {
    float vals[4];
    compute_vals(Qt, t_ptr, vals);
    int e = blockIdx.x * blockDim.x + threadIdx.x;
    int i = et[e];
    int j = et[N_EDGES + e];
    if (i < j) out[tri_idx(i, j)] = vals[1];
}

// Pass 3: x_start edges (i<j): read tag LSB, select vals[3] (tag kept 1) or
// vals[2] (tag kept 0). Idempotent under duplicate-edge races.
__global__ void gt_scatter_s(const float* __restrict__ Qt,
                             const int* __restrict__ t_ptr,
                             const int* __restrict__ es,
                             float* __restrict__ out) {
    float vals[4];
    compute_vals(Qt, t_ptr, vals);
    int e = blockIdx.x * blockDim.x + threadIdx.x;
    int i = es[e];
    int j = es[N_EDGES + e];
    if (i < j) {
        int idx = tri_idx(i, j);
        uint32_t cur = __float_as_uint(out[idx]);
        out[idx] = (cur & 1u) ? vals[3] : vals[2];
    }
}

extern "C" void kernel_launch(void* const* d_in, const int* in_sizes, int n_in,
                              void* d_out, int out_size, void* d_ws, size_t ws_size,
                              hipStream_t stream) {
    const float* Qt = (const float*)d_in[0];
    const int* et = (const int*)d_in[1];
    const int* es = (const int*)d_in[2];
    const int* t_ptr = (const int*)d_in[3];
    float* out = (float*)d_out;

    gt_fill_default<<<OUT_QUADS / 256, 256, 0, stream>>>(Qt, t_ptr, (float4*)out);
    gt_scatter_t<<<N_EDGES / 256, 256, 0, stream>>>(Qt, t_ptr, et, out);
    gt_scatter_s<<<N_EDGES / 256, 256, 0, stream>>>(Qt, t_ptr, es, out);
}